// Round 1
// baseline (4055.762 us; speedup 1.0000x reference)
//
#include <hip/hip_runtime.h>

// LightGCL forward: 2 layers of bipartite SpMM + mean of layer embeddings.
// Inputs: user_emb [nu*64] f32, item_emb [ni*64] f32,
//         adj_vals [nnz] f32, adj_rows [nnz] i32, adj_cols [nnz] i32
// Output: concat(sum_u/3 [nu*64], sum_i/3 [ni*64]) f32

constexpr int D = 64;

// One thread per (edge, dim). 64 consecutive threads share one edge:
// index/val loads broadcast, gathers/atomics are coalesced 256B rows.
__global__ void spmm_edge(const float* __restrict__ vals,
                          const int* __restrict__ rows,
                          const int* __restrict__ cols,
                          const float* __restrict__ Eu,
                          const float* __restrict__ Ei,
                          float* __restrict__ Zu,
                          float* __restrict__ Zi,
                          float scale, int nnz) {
    long long gid = (long long)blockIdx.x * blockDim.x + threadIdx.x;
    if (gid >= (long long)nnz * D) return;
    int e = (int)(gid >> 6);
    int d = (int)(gid & 63);
    float v = vals[e] * scale;
    long long r = rows[e];
    long long c = cols[e];
    float ei = Ei[c * D + d];
    float eu = Eu[r * D + d];
    // Z_u[r] += v * E_i[c] ; Z_i[c] += v * E_u[r]
    atomicAdd(&Zu[r * D + d], v * ei);
    atomicAdd(&Zi[c * D + d], v * eu);
}

// out = (E0 + Z1) * (1/3), vectorized float4. Fully overwrites out, so the
// following layer-2 atomics accumulate into a deterministic base.
__global__ void combine(const float* __restrict__ E0,
                        const float* __restrict__ Z1,
                        float* __restrict__ out, long long n4) {
    long long i = (long long)blockIdx.x * blockDim.x + threadIdx.x;
    if (i >= n4) return;
    const float4 a = reinterpret_cast<const float4*>(E0)[i];
    const float4 b = reinterpret_cast<const float4*>(Z1)[i];
    const float inv3 = 1.0f / 3.0f;
    float4 o;
    o.x = (a.x + b.x) * inv3;
    o.y = (a.y + b.y) * inv3;
    o.z = (a.z + b.z) * inv3;
    o.w = (a.w + b.w) * inv3;
    reinterpret_cast<float4*>(out)[i] = o;
}

extern "C" void kernel_launch(void* const* d_in, const int* in_sizes, int n_in,
                              void* d_out, int out_size, void* d_ws, size_t ws_size,
                              hipStream_t stream) {
    const float* user_emb = (const float*)d_in[0];
    const float* item_emb = (const float*)d_in[1];
    const float* vals     = (const float*)d_in[2];
    const int*   rows     = (const int*)d_in[3];
    const int*   cols     = (const int*)d_in[4];

    const int nu  = in_sizes[0] / D;   // 100000
    const int ni  = in_sizes[1] / D;   // 200000
    const int nnz = in_sizes[2];       // 5000000

    float* Zu1 = (float*)d_ws;                    // [nu*D]
    float* Zi1 = Zu1 + (size_t)nu * D;            // [ni*D]
    float* out_u = (float*)d_out;                 // [nu*D]
    float* out_i = out_u + (size_t)nu * D;        // [ni*D]

    // Zero layer-1 accumulators (76.8 MB).
    hipMemsetAsync(d_ws, 0, (size_t)(nu + ni) * D * sizeof(float), stream);

    const int threads = 256;
    long long tot = (long long)nnz * D;
    unsigned blocks = (unsigned)((tot + threads - 1) / threads);

    // Layer 1: Zu1 = A @ item_emb ; Zi1 = A^T @ user_emb
    spmm_edge<<<blocks, threads, 0, stream>>>(vals, rows, cols,
                                              user_emb, item_emb,
                                              Zu1, Zi1, 1.0f, nnz);

    // out = (E0 + Z1) / 3
    long long nu4 = (long long)nu * D / 4;
    long long ni4 = (long long)ni * D / 4;
    combine<<<(unsigned)((nu4 + 255) / 256), 256, 0, stream>>>(user_emb, Zu1, out_u, nu4);
    combine<<<(unsigned)((ni4 + 255) / 256), 256, 0, stream>>>(item_emb, Zi1, out_i, ni4);

    // Layer 2 accumulated straight into out, pre-scaled by 1/3:
    // out_u += (1/3) * A @ Zi1 ; out_i += (1/3) * A^T @ Zu1
    spmm_edge<<<blocks, threads, 0, stream>>>(vals, rows, cols,
                                              Zu1, Zi1,
                                              out_u, out_i, 1.0f / 3.0f, nnz);
}

// Round 2
// 2897.830 us; speedup vs baseline: 1.3996x; 1.3996x over previous
//
#include <hip/hip_runtime.h>

// LightGCL forward: 2 layers of bipartite SpMM + mean of layer embeddings.
// Strategy: build CSR(users)+CSC(items) on device each call (int atomics only),
// then 4 pull-style SpMMs with zero float atomics. Layer-2 pulls fuse the
// (E0 + Z1 + Z2)/3 combine.

constexpr int D = 64;
constexpr int SCAN_BLOCK = 256;
constexpr int SCAN_ITEMS = 4;
constexpr int SCAN_TILE  = SCAN_BLOCK * SCAN_ITEMS;  // 1024

// ---------------- CSR build ----------------

__global__ void hist_kernel(const int* __restrict__ rows,
                            const int* __restrict__ cols,
                            int* __restrict__ cnt, int nu, int nnz) {
    int e = blockIdx.x * blockDim.x + threadIdx.x;
    if (e >= nnz) return;
    atomicAdd(&cnt[rows[e]], 1);
    atomicAdd(&cnt[nu + cols[e]], 1);
}

// Per-block exclusive scan over tiles of 1024; writes per-block partial
// exclusive scans into ptr and the block total into bsum[bid].
__global__ void scan1_kernel(const int* __restrict__ cnt, int* __restrict__ ptr,
                             int* __restrict__ bsum, int n) {
    __shared__ int lds[SCAN_BLOCK];
    int t = threadIdx.x;
    int base = blockIdx.x * SCAN_TILE + t * SCAN_ITEMS;
    int v[SCAN_ITEMS];
    int s = 0;
#pragma unroll
    for (int k = 0; k < SCAN_ITEMS; k++) {
        int i = base + k;
        v[k] = (i < n) ? cnt[i] : 0;
        s += v[k];
    }
    lds[t] = s;
    __syncthreads();
    for (int off = 1; off < SCAN_BLOCK; off <<= 1) {
        int x = (t >= off) ? lds[t - off] : 0;
        __syncthreads();
        lds[t] += x;
        __syncthreads();
    }
    if (t == SCAN_BLOCK - 1) bsum[blockIdx.x] = lds[t];
    int excl = (t > 0) ? lds[t - 1] : 0;
#pragma unroll
    for (int k = 0; k < SCAN_ITEMS; k++) {
        int i = base + k;
        if (i < n) { ptr[i] = excl; excl += v[k]; }
    }
}

// Single-block exclusive scan of the block sums (nb <= 512).
__global__ void scan2_kernel(int* __restrict__ bsum, int nb) {
    __shared__ int lds[512];
    int t = threadIdx.x;
    int v = (t < nb) ? bsum[t] : 0;
    lds[t] = v;
    __syncthreads();
    for (int off = 1; off < 512; off <<= 1) {
        int x = (t >= off) ? lds[t - off] : 0;
        __syncthreads();
        lds[t] += x;
        __syncthreads();
    }
    if (t < nb) bsum[t] = lds[t] - v;  // exclusive
}

// Add block offsets; also copy to cur[] (fill cursors) and set ptr[n]=total.
__global__ void scan3_kernel(int* __restrict__ ptr, int* __restrict__ cur,
                             const int* __restrict__ bsum, int n, int total) {
    int i = blockIdx.x * blockDim.x + threadIdx.x;
    if (i < n) {
        int p = ptr[i] + bsum[i / SCAN_TILE];
        ptr[i] = p;
        cur[i] = p;
    }
    if (i == n) ptr[n] = total;
}

// Scatter each edge into its row's slot range (both directions).
// slot = (src_index, val_bits) packed as int2 for a single 8B store.
__global__ void fill_kernel(const float* __restrict__ vals,
                            const int* __restrict__ rows,
                            const int* __restrict__ cols,
                            int* __restrict__ cur, int2* __restrict__ slots,
                            int nu, int nnz) {
    int e = blockIdx.x * blockDim.x + threadIdx.x;
    if (e >= nnz) return;
    int r = rows[e], c = cols[e];
    int iv = __float_as_int(vals[e]);
    int pu = atomicAdd(&cur[r], 1);
    slots[pu] = make_int2(c, iv);
    int pi = atomicAdd(&cur[nu + c], 1);
    slots[pi] = make_int2(r, iv);
}

// ---------------- pull SpMM ----------------
// One block (256 thr = 4 waves) per destination row. Lane d = dim, wave j
// handles edges beg+j, beg+j+4, ... Gathers are coalesced 256B rows; the
// slot load broadcasts within a wave. No atomics; one coalesced write.
// FUSE: out[row] = (E0[row] + Z1[row] + sum) / 3   (layer-2 + combine)
// else: out[row] = sum                              (layer-1)
template <bool FUSE>
__global__ void pull_kernel(const int2* __restrict__ slots,
                            const int* __restrict__ ptr,
                            const float* __restrict__ Esrc,
                            const float* __restrict__ E0,
                            const float* __restrict__ Z1,
                            float* __restrict__ outp, int rowBase) {
    __shared__ float lds[256];
    int row = blockIdx.x;
    int t = threadIdx.x;
    int d = t & 63, j = t >> 6;
    int pr = rowBase + row;
    int beg = ptr[pr], end = ptr[pr + 1];
    float acc = 0.f;
    for (int e = beg + j; e < end; e += 4) {
        int2 s = slots[e];
        acc += __int_as_float(s.y) * Esrc[(long long)s.x * D + d];
    }
    lds[t] = acc;
    __syncthreads();
    if (t < 64) {
        float sum = lds[t] + lds[64 + t] + lds[128 + t] + lds[192 + t];
        long long o = (long long)row * D + d;
        if (FUSE)
            outp[o] = (E0[o] + Z1[o] + sum) * (1.f / 3.f);
        else
            outp[o] = sum;
    }
}

// ---------------- fallback (atomic scatter, needs only 77 MB ws) ----------------

__global__ void spmm_edge(const float* __restrict__ vals,
                          const int* __restrict__ rows,
                          const int* __restrict__ cols,
                          const float* __restrict__ Eu,
                          const float* __restrict__ Ei,
                          float* __restrict__ Zu, float* __restrict__ Zi,
                          float scale, int nnz) {
    long long gid = (long long)blockIdx.x * blockDim.x + threadIdx.x;
    if (gid >= (long long)nnz * D) return;
    int e = (int)(gid >> 6);
    int d = (int)(gid & 63);
    float v = vals[e] * scale;
    long long r = rows[e];
    long long c = cols[e];
    atomicAdd(&Zu[r * D + d], v * Ei[c * D + d]);
    atomicAdd(&Zi[c * D + d], v * Eu[r * D + d]);
}

__global__ void combine_kernel(const float* __restrict__ E0,
                               const float* __restrict__ Z1,
                               float* __restrict__ out, long long n4) {
    long long i = (long long)blockIdx.x * blockDim.x + threadIdx.x;
    if (i >= n4) return;
    const float4 a = reinterpret_cast<const float4*>(E0)[i];
    const float4 b = reinterpret_cast<const float4*>(Z1)[i];
    const float inv3 = 1.0f / 3.0f;
    float4 o;
    o.x = (a.x + b.x) * inv3;
    o.y = (a.y + b.y) * inv3;
    o.z = (a.z + b.z) * inv3;
    o.w = (a.w + b.w) * inv3;
    reinterpret_cast<float4*>(out)[i] = o;
}

// ---------------- launcher ----------------

static inline size_t align256(size_t x) { return (x + 255) & ~(size_t)255; }

extern "C" void kernel_launch(void* const* d_in, const int* in_sizes, int n_in,
                              void* d_out, int out_size, void* d_ws, size_t ws_size,
                              hipStream_t stream) {
    const float* user_emb = (const float*)d_in[0];
    const float* item_emb = (const float*)d_in[1];
    const float* vals     = (const float*)d_in[2];
    const int*   rows     = (const int*)d_in[3];
    const int*   cols     = (const int*)d_in[4];

    const int nu  = in_sizes[0] / D;  // 100000
    const int ni  = in_sizes[1] / D;  // 200000
    const int nnz = in_sizes[2];      // 5000000
    const int nR  = nu + ni;

    float* out_u = (float*)d_out;
    float* out_i = out_u + (size_t)nu * D;

    // ws layout
    size_t off = 0;
    size_t sz_slots = (size_t)2 * nnz * sizeof(int2);
    size_t sz_Z     = (size_t)nR * D * sizeof(float);
    size_t sz_cnt   = (size_t)nR * sizeof(int);
    size_t sz_ptr   = (size_t)(nR + 1) * sizeof(int);
    size_t sz_bsum  = 512 * sizeof(int);

    size_t o_slots = off;            off += align256(sz_slots);
    size_t o_Z     = off;            off += align256(sz_Z);
    size_t o_cnt   = off;            off += align256(sz_cnt);
    size_t o_ptr   = off;            off += align256(sz_ptr);
    size_t o_cur   = off;            off += align256(sz_cnt);
    size_t o_bsum  = off;            off += align256(sz_bsum);
    size_t needed  = off;

    if (ws_size >= needed) {
        char* w = (char*)d_ws;
        int2*  slots = (int2*)(w + o_slots);
        float* Zu1   = (float*)(w + o_Z);
        float* Zi1   = Zu1 + (size_t)nu * D;
        int*   cnt   = (int*)(w + o_cnt);
        int*   ptr   = (int*)(w + o_ptr);
        int*   cur   = (int*)(w + o_cur);
        int*   bsum  = (int*)(w + o_bsum);

        hipMemsetAsync(cnt, 0, sz_cnt, stream);

        const int T = 256;
        unsigned gE = (unsigned)((nnz + T - 1) / T);
        hist_kernel<<<gE, T, 0, stream>>>(rows, cols, cnt, nu, nnz);

        int nb = (nR + SCAN_TILE - 1) / SCAN_TILE;  // 293 for 300k
        scan1_kernel<<<nb, SCAN_BLOCK, 0, stream>>>(cnt, ptr, bsum, nR);
        scan2_kernel<<<1, 512, 0, stream>>>(bsum, nb);
        scan3_kernel<<<(unsigned)((nR + 1 + T - 1) / T), T, 0, stream>>>(
            ptr, cur, bsum, nR, 2 * nnz);

        fill_kernel<<<gE, T, 0, stream>>>(vals, rows, cols, cur, slots, nu, nnz);

        // Layer 1: Zu1 = A @ Ei0 ; Zi1 = A^T @ Eu0
        pull_kernel<false><<<nu, 256, 0, stream>>>(slots, ptr, item_emb,
                                                   nullptr, nullptr, Zu1, 0);
        pull_kernel<false><<<ni, 256, 0, stream>>>(slots, ptr, user_emb,
                                                   nullptr, nullptr, Zi1, nu);
        // Layer 2 fused with combine:
        // out_u = (Eu0 + Zu1 + A @ Zi1) / 3 ; out_i = (Ei0 + Zi1 + A^T @ Zu1) / 3
        pull_kernel<true><<<nu, 256, 0, stream>>>(slots, ptr, Zi1,
                                                  user_emb, Zu1, out_u, 0);
        pull_kernel<true><<<ni, 256, 0, stream>>>(slots, ptr, Zu1,
                                                  item_emb, Zi1, out_i, nu);
    } else {
        // Fallback: atomic scatter (round-1 path), needs only (nu+ni)*D*4 bytes.
        float* Zu1 = (float*)d_ws;
        float* Zi1 = Zu1 + (size_t)nu * D;
        hipMemsetAsync(d_ws, 0, (size_t)nR * D * sizeof(float), stream);

        const int threads = 256;
        long long tot = (long long)nnz * D;
        unsigned blocks = (unsigned)((tot + threads - 1) / threads);

        spmm_edge<<<blocks, threads, 0, stream>>>(vals, rows, cols, user_emb,
                                                  item_emb, Zu1, Zi1, 1.0f, nnz);
        long long nu4 = (long long)nu * D / 4;
        long long ni4 = (long long)ni * D / 4;
        combine_kernel<<<(unsigned)((nu4 + 255) / 256), 256, 0, stream>>>(
            user_emb, Zu1, out_u, nu4);
        combine_kernel<<<(unsigned)((ni4 + 255) / 256), 256, 0, stream>>>(
            item_emb, Zi1, out_i, ni4);
        spmm_edge<<<blocks, threads, 0, stream>>>(vals, rows, cols, Zu1, Zi1,
                                                  out_u, out_i, 1.0f / 3.0f, nnz);
    }
}